// Round 8
// baseline (222.100 us; speedup 1.0000x reference)
//
#include <hip/hip_runtime.h>

#define D 128
#define NSEG 4096
#define EPS 1e-5f
#define RG 16          // row groups (512 threads / 32 col groups)
#define CAP 22         // register-resident rows per thread -> 352 rows/block

typedef float f32x4 __attribute__((ext_vector_type(4)));

// Single-pass register-resident instance norm. One kernel: each block binary
// searches its segment bounds (broadcast loads, L2/L3-hot), holds its chunk
// in VGPRs across the stats reduction, then normalizes from registers.
// x is read from HBM exactly once; NT on both streams.
__global__ __launch_bounds__(512) void inorm_seg_kernel(
    const float* __restrict__ x,
    const int* __restrict__ batch,
    const float* __restrict__ weight,
    const float* __restrict__ bias,
    float* __restrict__ out,
    int N)
{
    const int g = blockIdx.x;

    // Binary search segment bounds (all threads redundantly; same addresses
    // -> broadcast transactions).
    int lo = 0, hi = N;
    while (lo < hi) { int mid = (lo + hi) >> 1; if (batch[mid] < g) lo = mid + 1; else hi = mid; }
    const int start = lo;
    hi = N;
    while (lo < hi) { int mid = (lo + hi) >> 1; if (batch[mid] <= g) lo = mid + 1; else hi = mid; }
    const int end = lo;
    const int cnt = end - start;
    if (cnt == 0) return;

    const int tid = threadIdx.x;
    const int rg  = tid >> 5;        // row group 0..15
    const int cg  = tid & 31;        // cols [cg*4, cg*4+4)
    const int c0  = cg * 4;
    const int Nm1 = N - 1;
    const int rbase = start + rg;

    // ---- Load phase: CAP independent NT loads, all in flight at once.
    // Out-of-segment rows clamp to a valid address; masked to 0 below.
    f32x4 v[CAP];
    #pragma unroll
    for (int k = 0; k < CAP; ++k) {
        const int r  = rbase + k * RG;
        const int rc = min(r, Nm1);
        v[k] = __builtin_nontemporal_load((const f32x4*)(x + (size_t)rc * D + c0));
    }

    // ---- Accumulate sum / sum-of-squares (masked).
    f32x4 s = (f32x4)(0.f);
    f32x4 q = (f32x4)(0.f);
    #pragma unroll
    for (int k = 0; k < CAP; ++k) {
        const int r  = rbase + k * RG;
        const float mk = (r < end) ? 1.0f : 0.0f;
        const f32x4 vm = v[k] * mk;
        s += vm;
        q += vm * v[k];
    }
    // Overflow rows (segment > 352 rows; ~never for this distribution).
    for (int r = rbase + CAP * RG; r < end; r += RG) {
        const f32x4 vv = *(const f32x4*)(x + (size_t)r * D + c0);
        s += vv;
        q += vv * vv;
    }

    // ---- Block reduction over the 16 row groups; sum and sq in parallel.
    __shared__ float s_sum[RG][D];
    __shared__ float s_sq[RG][D];
    *(f32x4*)&s_sum[rg][c0] = s;
    *(f32x4*)&s_sq[rg][c0]  = q;
    __syncthreads();

    __shared__ float s_red[2][D];    // [0]=sum, [1]=sumsq
    if (tid < 256) {
        const int which = tid >> 7;          // 0: sum, 1: sq
        const int col   = tid & 127;
        const float (*src)[D] = which ? s_sq : s_sum;
        float acc = 0.f;
        #pragma unroll
        for (int i = 0; i < RG; ++i) acc += src[i][col];
        s_red[which][col] = acc;
    }
    __syncthreads();

    __shared__ float s_mean[D];
    __shared__ float s_inv[D];
    if (tid < D) {
        const float c    = (float)cnt;
        const float mean = s_red[0][tid] / c;
        float var = s_red[1][tid] / c - mean * mean;
        var = fmaxf(var, 0.f);
        s_mean[tid] = mean;
        s_inv[tid]  = rsqrtf(var + EPS);
    }
    __syncthreads();

    // ---- Normalize from registers, streaming NT stores.
    const f32x4 m4 = *(const f32x4*)&s_mean[c0];
    const f32x4 i4 = *(const f32x4*)&s_inv[c0];
    const f32x4 w4 = *(const f32x4*)(weight + c0);
    const f32x4 b4 = *(const f32x4*)(bias + c0);
    const f32x4 sc = i4 * w4;

    #pragma unroll
    for (int k = 0; k < CAP; ++k) {
        const int r = rbase + k * RG;
        if (r < end) {
            const f32x4 y = (v[k] - m4) * sc + b4;
            __builtin_nontemporal_store(y, (f32x4*)(out + (size_t)r * D + c0));
        }
    }
    // Overflow rows: re-read (L2-hot) and normalize.
    for (int r = rbase + CAP * RG; r < end; r += RG) {
        const f32x4 vv = *(const f32x4*)(x + (size_t)r * D + c0);
        const f32x4 y  = (vv - m4) * sc + b4;
        __builtin_nontemporal_store(y, (f32x4*)(out + (size_t)r * D + c0));
    }
}

extern "C" void kernel_launch(void* const* d_in, const int* in_sizes, int n_in,
                              void* d_out, int out_size, void* d_ws, size_t ws_size,
                              hipStream_t stream) {
    const float* x      = (const float*)d_in[0];
    const int*   batch  = (const int*)d_in[1];
    const float* weight = (const float*)d_in[2];
    const float* bias   = (const float*)d_in[3];
    float*       out    = (float*)d_out;
    const int N = in_sizes[0] / D;

    inorm_seg_kernel<<<NSEG, 512, 0, stream>>>(x, batch, weight, bias, out, N);
}

// Round 9
// 191.135 us; speedup vs baseline: 1.1620x; 1.1620x over previous
//
#include <hip/hip_runtime.h>

#define D 128
#define NSEG 4096
#define EPS 1e-5f
#define RG 16          // row groups (512 threads / 32 col groups)
#define CAP 20         // register-resident rows per thread -> 320 rows/block

typedef float f32x4 __attribute__((ext_vector_type(4)));

// Kernel 0: starts[s] = first row index with batch[row] >= s, s in [0, NSEG].
__global__ void seg_starts_kernel(const int* __restrict__ batch,
                                  int* __restrict__ starts, int N) {
    int i = blockIdx.x * blockDim.x + threadIdx.x;
    if (i >= N) return;
    const int b = batch[i];
    const int a = (i == 0) ? -1 : batch[i - 1];
    for (int s = a + 1; s <= b; ++s) starts[s] = i;
    if (i == N - 1) {
        for (int s = b + 1; s <= NSEG; ++s) starts[s] = N;
    }
}

// Single-pass register-resident instance norm: x is read from HBM exactly
// once; the segment chunk lives in VGPRs across the stats reduction.
// Loads are exec-masked (no dummy clamped loads), stores are nontemporal.
__global__ __launch_bounds__(512) void inorm_seg_kernel(
    const float* __restrict__ x,
    const int* __restrict__ starts,
    const float* __restrict__ weight,
    const float* __restrict__ bias,
    float* __restrict__ out,
    int N)
{
    const int g     = blockIdx.x;
    const int start = starts[g];
    const int end   = starts[g + 1];
    const int cnt   = end - start;
    if (cnt == 0) return;

    const int tid = threadIdx.x;
    const int rg  = tid >> 5;        // row group 0..15
    const int cg  = tid & 31;        // cols [cg*4, cg*4+4)
    const int c0  = cg * 4;
    const int rbase = start + rg;

    // ---- Load phase: up to CAP independent exec-masked loads in flight.
    // Out-of-segment lanes load nothing and hold 0.
    f32x4 v[CAP];
    #pragma unroll
    for (int k = 0; k < CAP; ++k) {
        const int r = rbase + k * RG;
        if (r < end) v[k] = *(const f32x4*)(x + (size_t)r * D + c0);
        else         v[k] = (f32x4)(0.f);
    }

    // ---- Accumulate sum / sum-of-squares (zeros contribute nothing).
    f32x4 s = (f32x4)(0.f);
    f32x4 q = (f32x4)(0.f);
    #pragma unroll
    for (int k = 0; k < CAP; ++k) {
        s += v[k];
        q += v[k] * v[k];
    }
    // Overflow rows (segment > 320 rows; ~never for this distribution).
    for (int r = rbase + CAP * RG; r < end; r += RG) {
        const f32x4 vv = *(const f32x4*)(x + (size_t)r * D + c0);
        s += vv;
        q += vv * vv;
    }

    // ---- Block reduction over the 16 row groups.
    __shared__ float s_sum[RG][D];
    __shared__ float s_sq[RG][D];
    *(f32x4*)&s_sum[rg][c0] = s;
    *(f32x4*)&s_sq[rg][c0]  = q;
    __syncthreads();

    __shared__ float s_mean[D];
    __shared__ float s_inv[D];
    if (tid < D) {
        float sum = 0.f, sq = 0.f;
        #pragma unroll
        for (int i = 0; i < RG; ++i) { sum += s_sum[i][tid]; sq += s_sq[i][tid]; }
        const float c    = (float)cnt;
        const float mean = sum / c;
        float var = sq / c - mean * mean;
        var = fmaxf(var, 0.f);
        s_mean[tid] = mean;
        s_inv[tid]  = rsqrtf(var + EPS);
    }
    __syncthreads();

    // ---- Normalize from registers, streaming NT stores.
    const f32x4 m4 = *(const f32x4*)&s_mean[c0];
    const f32x4 i4 = *(const f32x4*)&s_inv[c0];
    const f32x4 w4 = *(const f32x4*)(weight + c0);
    const f32x4 b4 = *(const f32x4*)(bias + c0);
    const f32x4 sc = i4 * w4;

    #pragma unroll
    for (int k = 0; k < CAP; ++k) {
        const int r = rbase + k * RG;
        if (r < end) {
            const f32x4 y = (v[k] - m4) * sc + b4;
            __builtin_nontemporal_store(y, (f32x4*)(out + (size_t)r * D + c0));
        }
    }
    // Overflow rows: re-read (L2-hot) and normalize.
    for (int r = rbase + CAP * RG; r < end; r += RG) {
        const f32x4 vv = *(const f32x4*)(x + (size_t)r * D + c0);
        const f32x4 y  = (vv - m4) * sc + b4;
        __builtin_nontemporal_store(y, (f32x4*)(out + (size_t)r * D + c0));
    }
}

extern "C" void kernel_launch(void* const* d_in, const int* in_sizes, int n_in,
                              void* d_out, int out_size, void* d_ws, size_t ws_size,
                              hipStream_t stream) {
    const float* x      = (const float*)d_in[0];
    const int*   batch  = (const int*)d_in[1];
    const float* weight = (const float*)d_in[2];
    const float* bias   = (const float*)d_in[3];
    float*       out    = (float*)d_out;
    const int N = in_sizes[0] / D;

    int* starts = (int*)d_ws;   // NSEG+1 ints

    seg_starts_kernel<<<(N + 255) / 256, 256, 0, stream>>>(batch, starts, N);
    inorm_seg_kernel<<<NSEG, 512, 0, stream>>>(x, starts, weight, bias, out, N);
}